// Round 12
// baseline (74.400 us; speedup 1.0000x reference)
//
#include <hip/hip_runtime.h>

// Analytic collapse (verified R1-R10, absmax 9.8e-4):
//   <Z_0> = c1*...*c7,  <Z_j> = c0*...*cj,  c_j = cos(t_j + theta_j)
// R11 = R10 minus one barrier: attention is fused into the ODD (k-combine)
// waves, which hold the final z wave-locally (in-order DS, R2-verified), so
// P2 needs no barrier; it overlaps with waves 2,3 staging Wo. 3 barriers.
// 512 blocks x 512 thr; block = 16 tokens; ~65 KB LDS -> 2 blocks/CU.
//  P1: R6-verified swizzled-W reads + readlane-x (per-iter addr VALU kept --
//      throttles the load hoister; R7/R8's imm-offset avalanche spilled 226MB).
//  B2..B3 window: odd waves combine+cos+scan+ATTENTION on own 4 tokens;
//      waves 2,3 stage Wo into dead Wq region.
//  P3: 2 scrambled rows/wave; Wo row hoisted from LDS; scr via readlane.

#define WT  4096   // dwords per XOR-swizzled W matrix (32 kk * 128)
#define SPS 68     // sP row stride (16B-aligned rows)
#define SCS 68     // sScr row stride
#define WOS 66     // sWo row stride (overlaid on dead Wq/Wk region)

// d *= dpp_row_shr<sh>(d) gated to lanes with (lane&7) >= sh
#define DPP_SHR_STEP(d, j, sh)                                                 \
    {                                                                          \
        float _t = __int_as_float(__builtin_amdgcn_update_dpp(                 \
            0x3f800000, __float_as_int(d), 0x110 + sh, 0xf, 0xf, false));      \
        d *= ((j) >= (sh)) ? _t : 1.0f;                                        \
    }

__device__ __forceinline__ float rl(float v, int l) {
    return __int_as_float(__builtin_amdgcn_readlane(__float_as_int(v), l));
}

__global__ __launch_bounds__(512, 4)
void qattn_fused(const float* __restrict__ xg,
                 const float* __restrict__ wqg, const float* __restrict__ wkg,
                 const float* __restrict__ wvg, const float* __restrict__ wog,
                 const float* __restrict__ thg,
                 float* __restrict__ outg)
{
    __shared__ float sWt[3 * WT];                  // 48 KB  Wq,Wk,Wv swizzled
    __shared__ __align__(16) float sP[48 * SPS];   // 12.75 KB partials then z
    __shared__ __align__(16) float sScr[16 * SCS]; // 4.25 KB scrambled rows
    float* sWo = sWt;                              // overlays dead Wq/Wk in P3

    const int tid  = threadIdx.x;
    const int lane = tid & 63;
    const int wg   = tid >> 6;        // 0..7
    const int p    = wg & 3;          // token-quad pair id
    const int half = wg >> 2;         // k-half
    const int j    = lane & 7;
    const int b    = blockIdx.x >> 5;
    const int grp  = blockIdx.x & 31; // 16-token group in batch row

    // ---- stage Wq,Wk,Wv transposed + XOR-swizzled (R6 layout) ----
    {
        const float* gm[3] = {wqg, wkg, wvg};
        #pragma unroll
        for (int m = 0; m < 3; ++m) {
            #pragma unroll
            for (int r = 0; r < 2; ++r) {
                const int g = tid + 512 * r;            // float4 idx 0..1023
                const float4 v = ((const float4*)gm[m])[g];
                const int e = g >> 4, kq = g & 15;
                const int c0 = (2 * e + 4 * kq) & 127;
                const int c1 = (c0 + 2) & 127;
                *(float2*)&sWt[m * WT + 256 * kq + c0]       = make_float2(v.x, v.y);
                *(float2*)&sWt[m * WT + 256 * kq + 128 + c1] = make_float2(v.z, v.w);
            }
        }
    }
    // per-wave x rows (lane = column) for this pair's 4 tokens
    float xr[4];
    {
        const float* xb = xg + ((size_t)(b * 512 + grp * 16 + p * 4)) * 64 + lane;
        xr[0] = xb[0]; xr[1] = xb[64]; xr[2] = xb[128]; xr[3] = xb[192];
    }
    const float thf = thg[j];
    __syncthreads();                               // B1: sWt ready

    // ---- P1: half-k projections; lane = out elem e; 4 tokens ----
    float acc[3][4];
    #pragma unroll
    for (int m = 0; m < 3; ++m)
        #pragma unroll
        for (int t = 0; t < 4; ++t) acc[m][t] = 0.f;
    {
        const int kb0 = half * 16;
        #pragma unroll 8
        for (int kk = 0; kk < 16; ++kk) {
            const int kkg = kb0 + kk;
            const int col = (2 * lane + 2 * kkg) & 127;
            const float2 wq = *(const float2*)&sWt[0 * WT + kkg * 128 + col];
            const float2 wk = *(const float2*)&sWt[1 * WT + kkg * 128 + col];
            const float2 wv = *(const float2*)&sWt[2 * WT + kkg * 128 + col];
            #pragma unroll
            for (int t = 0; t < 4; ++t) {
                const float x0 = rl(xr[t], 2 * kkg);
                const float x1 = rl(xr[t], 2 * kkg + 1);
                acc[0][t] = fmaf(wq.x, x0, fmaf(wq.y, x1, acc[0][t]));
                acc[1][t] = fmaf(wk.x, x0, fmaf(wk.y, x1, acc[1][t]));
                acc[2][t] = fmaf(wv.x, x0, fmaf(wv.y, x1, acc[2][t]));
            }
        }
    }
    // even half writes raw partials (rows are this pair's canonical rows)
    if (half == 0) {
        #pragma unroll
        for (int m = 0; m < 3; ++m)
            #pragma unroll
            for (int t = 0; t < 4; ++t)
                sP[((p * 3 + m) * 4 + t) * SPS + lane] = acc[m][t];
    }
    __syncthreads();                               // B2: partials visible

    if (half == 1) {
        // ---- odd half: combine + cos + DPP scans -> final z (wave-local) ----
        #pragma unroll
        for (int m = 0; m < 3; ++m) {
            #pragma unroll
            for (int t = 0; t < 4; ++t) {
                const int base = ((p * 3 + m) * 4 + t) * SPS + lane;
                const float ang = acc[m][t] + sP[base] + thf;
                const float c = __cosf(ang);
                float d = c;                       // inclusive scan (c0..cj)
                DPP_SHR_STEP(d, j, 1)
                DPP_SHR_STEP(d, j, 2)
                DPP_SHR_STEP(d, j, 4)
                float ex = (j == 0) ? 1.0f : c;    // scan excluding c0
                DPP_SHR_STEP(ex, j, 1)
                DPP_SHR_STEP(ex, j, 2)
                DPP_SHR_STEP(ex, j, 4)
                if (j > 0)  sP[base]     = d;      // z_j = c0..cj
                if (j == 7) sP[base - 7] = ex;     // z_0 = c1..c7 into slot 0
            }
        }
        // ---- fused P2 (NO barrier: same-wave sP rows, in-order DS) ----
        // lane = (t = lane>>4 in [0,4), i = lane&7); bit3-set lanes duplicate.
        {
            const int t  = lane >> 4;
            const int i  = j;                      // head (score row)
            const int tt = p * 4 + t;              // block-local token 0..15
            const int qb = ((p * 3 + 0) * 4 + t) * SPS;
            const int kb = ((p * 3 + 1) * 4 + t) * SPS;
            const int vb = ((p * 3 + 2) * 4 + t) * SPS;
            float q[8];
            *(float4*)&q[0] = *(const float4*)&sP[qb + 8 * i];
            *(float4*)&q[4] = *(const float4*)&sP[qb + 8 * i + 4];
            float pr[8];
            float sum = 0.f;
            #pragma unroll
            for (int jj = 0; jj < 8; ++jj) {       // |s| <= 2.83 -> no max-sub
                const float4 k0 = *(const float4*)&sP[kb + 8 * jj];
                const float4 k1 = *(const float4*)&sP[kb + 8 * jj + 4];
                float s = q[0] * k0.x;
                s = fmaf(q[1], k0.y, s); s = fmaf(q[2], k0.z, s);
                s = fmaf(q[3], k0.w, s); s = fmaf(q[4], k1.x, s);
                s = fmaf(q[5], k1.y, s); s = fmaf(q[6], k1.z, s);
                s = fmaf(q[7], k1.w, s);
                pr[jj] = __expf(s * 0.35355339059327373f);
                sum += pr[jj];
            }
            const float rinv = 1.0f / sum;
            float o[8];
            #pragma unroll
            for (int w = 0; w < 8; ++w) o[w] = 0.f;
            #pragma unroll
            for (int jj = 0; jj < 8; ++jj) {
                const float4 v0 = *(const float4*)&sP[vb + 8 * jj];
                const float4 v1 = *(const float4*)&sP[vb + 8 * jj + 4];
                const float a = pr[jj] * rinv;
                o[0] = fmaf(a, v0.x, o[0]); o[1] = fmaf(a, v0.y, o[1]);
                o[2] = fmaf(a, v0.z, o[2]); o[3] = fmaf(a, v0.w, o[3]);
                o[4] = fmaf(a, v1.x, o[4]); o[5] = fmaf(a, v1.y, o[5]);
                o[6] = fmaf(a, v1.z, o[6]); o[7] = fmaf(a, v1.w, o[7]);
            }
            // scrambled row rho = i*2 + (tt>>3), col base 8*(tt&7)
            if (!(lane & 8)) {
                float* sd = &sScr[(i * 2 + (tt >> 3)) * SCS + 8 * (tt & 7)];
                *(float4*)sd       = make_float4(o[0], o[1], o[2], o[3]);
                *(float4*)(sd + 4) = make_float4(o[4], o[5], o[6], o[7]);
            }
        }
    } else if (wg >= 2) {
        // ---- waves 2,3: stage Wo (row-major, stride 66) over dead Wq/Wk ----
        const int lt = tid - 128;                  // 0..127
        #pragma unroll
        for (int r = 0; r < 8; ++r) {
            const int g = lt + 128 * r;            // float4 idx 0..1023
            const float4 v = ((const float4*)wog)[g];
            const int e = g >> 4, kq = g & 15;
            float* d = &sWo[e * WOS + 4 * kq];
            *(float2*)d       = make_float2(v.x, v.y);
            *(float2*)(d + 2) = make_float2(v.z, v.w);
        }
    }
    __syncthreads();                               // B3: sScr + sWo ready

    // ---- P3: y[rho] = scr[rho] . Wo[e]; lane = e; 2 rows per wave ----
    {
        float wo[64];
        #pragma unroll
        for (int c = 0; c < 32; ++c) {             // LDS row hoist, ~4-way b64
            const float2 v = *(const float2*)&sWo[lane * WOS + 2 * c];
            wo[2 * c] = v.x; wo[2 * c + 1] = v.y;
        }
        #pragma unroll
        for (int rr = 0; rr < 2; ++rr) {
            const int rho = wg * 2 + rr;
            const float sv = sScr[rho * SCS + lane];   // stride-1, conflict-free
            float y0 = 0.f, y1 = 0.f, y2 = 0.f, y3 = 0.f;
            #pragma unroll
            for (int k = 0; k < 64; k += 4) {
                y0 = fmaf(wo[k],     rl(sv, k),     y0);
                y1 = fmaf(wo[k + 1], rl(sv, k + 1), y1);
                y2 = fmaf(wo[k + 2], rl(sv, k + 2), y2);
                y3 = fmaf(wo[k + 3], rl(sv, k + 3), y3);
            }
            const float y = (y0 + y1) + (y2 + y3);
            const int head = rho >> 1, oct = rho & 1;
            outg[((size_t)(b * 512 + head * 64 + grp * 2 + oct)) * 64 + lane] = y;
        }
    }
}

extern "C" void kernel_launch(void* const* d_in, const int* in_sizes, int n_in,
                              void* d_out, int out_size, void* d_ws, size_t ws_size,
                              hipStream_t stream) {
    const float* x  = (const float*)d_in[0];
    const float* wq = (const float*)d_in[1];
    const float* wk = (const float*)d_in[2];
    const float* wv = (const float*)d_in[3];
    const float* wo = (const float*)d_in[4];
    const float* th = (const float*)d_in[5];
    float* out = (float*)d_out;
    // B=16, S=512: 16 batches x 32 sixteen-token groups = 512 blocks
    qattn_fused<<<dim3(512), dim3(512), 0, stream>>>(x, wq, wk, wv, wo, th, out);
}

// Round 13
// 66.909 us; speedup vs baseline: 1.1120x; 1.1120x over previous
//
#include <hip/hip_runtime.h>

// Analytic collapse (verified R1-R11, absmax 9.8e-4):
//   <Z_0> = c1*...*c7,  <Z_j> = c0*...*cj,  c_j = cos(t_j + theta_j)
// R12: MFMA rewrite. Block = 32 tokens; 256 blocks x 512 thr; ~115 KB LDS
// (1 block/CU; >64KB proven by R7's 71KB run). All GEMMs use
// mfma_f32_16x16x32_bf16 with SPLIT-BF16 operands (hi+lo, 3 MFMAs:
// hh+hl+lh -> ~2^-16 rel error, reproduces the fp32 path; plain bf16 would
// risk the 9.26e-3 absmax budget).
// Layouts (guide-verified): A[m=lane&15][k=(lane>>4)*8+j]; B[k][n=lane&15]
// symmetric; C col=lane&15(=e), row=(lane>>4)*4+reg(=token) -> DPP scans
// over lane&7 survive unchanged. Rows padded to 72 bf16 (144B): frag b128s
// start at 4*(9e+quad) banks -> conflict-free (8-cyc minimum).
//  P1: 24 (mat,ntile,mtile) tile-jobs, 3/wave: 6+ MFMA, cos+DPP scan epilogue.
//  P2 (waves 0-3): R10's verified row-per-lane attention, fp32, 8 tok/wave;
//      writes scrambled rows as split-bf16.
//  P3: 8 (mtile,ntile) jobs, 1/wave: 6 MFMA, direct coalesced global store.

typedef float  f32x4  __attribute__((ext_vector_type(4)));
typedef short  bf16x8 __attribute__((ext_vector_type(8)));
typedef unsigned short u16;
typedef unsigned int   u32;

#define WRS 72   // shorts per row (64 data + 8 pad) = 144 B, 16B-aligned
#define SPS 68   // sP row stride (dwords), 16B-aligned

// d *= dpp_row_shr<sh>(d) gated to lanes with (lane&7) >= sh
#define DPP_SHR_STEP(d, j, sh)                                                 \
    {                                                                          \
        float _t = __int_as_float(__builtin_amdgcn_update_dpp(                 \
            0x3f800000, __float_as_int(d), 0x110 + sh, 0xf, 0xf, false));      \
        d *= ((j) >= (sh)) ? _t : 1.0f;                                        \
    }

__device__ __forceinline__ u32 bfh(float f) {          // RTNE bf16 (raw u16)
    const u32 u = __float_as_uint(f);
    return (u + 0x7FFFu + ((u >> 16) & 1u)) >> 16;
}
__device__ __forceinline__ void bfsplit(float f, u32& h, u32& l) {
    h = bfh(f);
    l = bfh(f - __uint_as_float(h << 16));
}

#define MFMA3(acc, ah, al, bh, bl)                                             \
    acc = __builtin_amdgcn_mfma_f32_16x16x32_bf16(al, bh, acc, 0, 0, 0);       \
    acc = __builtin_amdgcn_mfma_f32_16x16x32_bf16(ah, bl, acc, 0, 0, 0);       \
    acc = __builtin_amdgcn_mfma_f32_16x16x32_bf16(ah, bh, acc, 0, 0, 0);

__global__ __launch_bounds__(512, 1)
void qattn_fused(const float* __restrict__ xg,
                 const float* __restrict__ wqg, const float* __restrict__ wkg,
                 const float* __restrict__ wvg, const float* __restrict__ wog,
                 const float* __restrict__ thg,
                 float* __restrict__ outg)
{
    __shared__ u16 sWh[4 * 64 * WRS];              // 36.9 KB  W hi (q,k,v,o)
    __shared__ u16 sWl[4 * 64 * WRS];              // 36.9 KB  W lo
    __shared__ u16 sXh[32 * WRS];                  // 4.6 KB   x hi
    __shared__ u16 sXl[32 * WRS];                  // 4.6 KB   x lo
    __shared__ __align__(16) float sP[96 * SPS];   // 26.1 KB  z values [m*32+t][e]
    __shared__ u16 sSh[32 * WRS];                  // 4.6 KB   scr hi [rho][col]
    __shared__ u16 sSl[32 * WRS];                  // 4.6 KB   scr lo

    const int tid  = threadIdx.x;
    const int lane = tid & 63;
    const int wg   = tid >> 6;         // 0..7
    const int l15  = lane & 15;
    const int quad = lane >> 4;
    const int j    = lane & 7;
    const int b    = blockIdx.x >> 4;
    const int grp  = blockIdx.x & 15;  // 32-token group in batch row

    // ---- stage W (4 matrices) as split bf16, padded rows ----
    {
        const float* gm[4] = {wqg, wkg, wvg, wog};
        #pragma unroll
        for (int r = 0; r < 8; ++r) {
            const int m   = r >> 1;
            const int idx = (r & 1) * 512 + tid;         // float4 idx in matrix
            const float4 v = ((const float4*)gm[m])[idx];
            const int e = idx >> 4, c = idx & 15;
            u32 h0, l0, h1, l1, h2, l2, h3, l3;
            bfsplit(v.x, h0, l0); bfsplit(v.y, h1, l1);
            bfsplit(v.z, h2, l2); bfsplit(v.w, h3, l3);
            const int o = (m * 64 + e) * WRS + 4 * c;
            *(uint2*)&sWh[o] = make_uint2(h0 | (h1 << 16), h2 | (h3 << 16));
            *(uint2*)&sWl[o] = make_uint2(l0 | (l1 << 16), l2 | (l3 << 16));
        }
    }
    // ---- stage x (32 tokens) as split bf16 ----
    {
        const float4 v = ((const float4*)(xg + (size_t)(b * 512 + grp * 32) * 64))[tid];
        const int t = tid >> 4, c = tid & 15;
        u32 h0, l0, h1, l1, h2, l2, h3, l3;
        bfsplit(v.x, h0, l0); bfsplit(v.y, h1, l1);
        bfsplit(v.z, h2, l2); bfsplit(v.w, h3, l3);
        const int o = t * WRS + 4 * c;
        *(uint2*)&sXh[o] = make_uint2(h0 | (h1 << 16), h2 | (h3 << 16));
        *(uint2*)&sXl[o] = make_uint2(l0 | (l1 << 16), l2 | (l3 << 16));
    }
    const float thf = thg[j];
    __syncthreads();                                 // B1: stages ready

    // ---- P1: projections via MFMA; 3 tile-jobs per wave ----
    #pragma unroll
    for (int ia = 0; ia < 3; ++ia) {
        const int aid = wg * 3 + ia;                 // 0..23
        const int mt = aid & 1, nt = (aid >> 1) & 3, m = aid >> 3;
        const int arow = (mt * 16 + l15) * WRS + quad * 8;
        const int brow = (m * 64 + nt * 16 + l15) * WRS + quad * 8;
        const bf16x8 ah0 = *(const bf16x8*)&sXh[arow];
        const bf16x8 ah1 = *(const bf16x8*)&sXh[arow + 32];
        const bf16x8 al0 = *(const bf16x8*)&sXl[arow];
        const bf16x8 al1 = *(const bf16x8*)&sXl[arow + 32];
        const bf16x8 bh0 = *(const bf16x8*)&sWh[brow];
        const bf16x8 bh1 = *(const bf16x8*)&sWh[brow + 32];
        const bf16x8 bl0 = *(const bf16x8*)&sWl[brow];
        const bf16x8 bl1 = *(const bf16x8*)&sWl[brow + 32];
        f32x4 acc = {0.f, 0.f, 0.f, 0.f};
        MFMA3(acc, ah0, al0, bh0, bl0)               // k = 0..31
        MFMA3(acc, ah1, al1, bh1, bl1)               // k = 32..63
        // epilogue: lane holds q[token][e] for 4 tokens; e = nt*16 + l15
        #pragma unroll
        for (int r = 0; r < 4; ++r) {
            const float c = __cosf(acc[r] + thf);
            float d = c;                             // inclusive scan (c0..cj)
            DPP_SHR_STEP(d, j, 1)
            DPP_SHR_STEP(d, j, 2)
            DPP_SHR_STEP(d, j, 4)
            float ex = (j == 0) ? 1.0f : c;          // scan excluding c0
            DPP_SHR_STEP(ex, j, 1)
            DPP_SHR_STEP(ex, j, 2)
            DPP_SHR_STEP(ex, j, 4)
            const int row  = m * 32 + mt * 16 + quad * 4 + r;
            const int base = row * SPS + nt * 16 + l15;
            if (j > 0)  sP[base]     = d;            // z_j = c0..cj
            if (j == 7) sP[base - 7] = ex;           // z_0 = c1..c7 -> slot 0
        }
    }
    __syncthreads();                                 // B2: z ready

    // ---- P2 (waves 0-3): row-per-lane attention, 8 tokens/wave (R10 math) ----
    if (wg < 4) {
        const int tg = wg * 8 + (lane >> 3);         // block-local token 0..31
        const int i  = j;                            // head (score row)
        const int qb = tg * SPS;
        const int kb = (32 + tg) * SPS;
        const int vb = (64 + tg) * SPS;
        float q[8];
        *(float4*)&q[0] = *(const float4*)&sP[qb + 8 * i];
        *(float4*)&q[4] = *(const float4*)&sP[qb + 8 * i + 4];
        float pr[8];
        float sum = 0.f;
        #pragma unroll
        for (int jj = 0; jj < 8; ++jj) {             // |s| <= 2.83 -> no max-sub
            const float4 k0 = *(const float4*)&sP[kb + 8 * jj];
            const float4 k1 = *(const float4*)&sP[kb + 8 * jj + 4];
            float s = q[0] * k0.x;
            s = fmaf(q[1], k0.y, s); s = fmaf(q[2], k0.z, s);
            s = fmaf(q[3], k0.w, s); s = fmaf(q[4], k1.x, s);
            s = fmaf(q[5], k1.y, s); s = fmaf(q[6], k1.z, s);
            s = fmaf(q[7], k1.w, s);
            pr[jj] = __expf(s * 0.35355339059327373f);
            sum += pr[jj];
        }
        const float rinv = 1.0f / sum;
        float o[8];
        #pragma unroll
        for (int w = 0; w < 8; ++w) o[w] = 0.f;
        #pragma unroll
        for (int jj = 0; jj < 8; ++jj) {
            const float4 v0 = *(const float4*)&sP[vb + 8 * jj];
            const float4 v1 = *(const float4*)&sP[vb + 8 * jj + 4];
            const float a = pr[jj] * rinv;
            o[0] = fmaf(a, v0.x, o[0]); o[1] = fmaf(a, v0.y, o[1]);
            o[2] = fmaf(a, v0.z, o[2]); o[3] = fmaf(a, v0.w, o[3]);
            o[4] = fmaf(a, v1.x, o[4]); o[5] = fmaf(a, v1.y, o[5]);
            o[6] = fmaf(a, v1.z, o[6]); o[7] = fmaf(a, v1.w, o[7]);
        }
        // scrambled row rho = i*4 + (tg>>3); col base 8*(tg&7); split-bf16
        u32 hh[4], ll[4];
        #pragma unroll
        for (int c = 0; c < 4; ++c) {
            u32 ha, la, hb, lb;
            bfsplit(o[2 * c], ha, la);
            bfsplit(o[2 * c + 1], hb, lb);
            hh[c] = ha | (hb << 16);
            ll[c] = la | (lb << 16);
        }
        const int so = (i * 4 + (tg >> 3)) * WRS + 8 * (tg & 7);
        *(uint4*)&sSh[so] = make_uint4(hh[0], hh[1], hh[2], hh[3]);
        *(uint4*)&sSl[so] = make_uint4(ll[0], ll[1], ll[2], ll[3]);
    }
    __syncthreads();                                 // B3: scr ready

    // ---- P3: y = scr @ Wo^T via MFMA; 1 tile-job per wave ----
    {
        const int mt2 = wg >> 2, nt2 = wg & 3;
        const int arow = (mt2 * 16 + l15) * WRS + quad * 8;
        const int brow = (3 * 64 + nt2 * 16 + l15) * WRS + quad * 8;
        const bf16x8 ah0 = *(const bf16x8*)&sSh[arow];
        const bf16x8 ah1 = *(const bf16x8*)&sSh[arow + 32];
        const bf16x8 al0 = *(const bf16x8*)&sSl[arow];
        const bf16x8 al1 = *(const bf16x8*)&sSl[arow + 32];
        const bf16x8 bh0 = *(const bf16x8*)&sWh[brow];
        const bf16x8 bh1 = *(const bf16x8*)&sWh[brow + 32];
        const bf16x8 bl0 = *(const bf16x8*)&sWl[brow];
        const bf16x8 bl1 = *(const bf16x8*)&sWl[brow + 32];
        f32x4 acc = {0.f, 0.f, 0.f, 0.f};
        MFMA3(acc, ah0, al0, bh0, bl0)
        MFMA3(acc, ah1, al1, bh1, bl1)
        // store: lane holds y[rho][e] for 4 rho; rho -> global row
        const int e = nt2 * 16 + l15;
        #pragma unroll
        for (int r = 0; r < 4; ++r) {
            const int rho = mt2 * 16 + quad * 4 + r;
            const int R   = (rho >> 2) * 64 + grp * 4 + (rho & 3);
            outg[((size_t)(b * 512 + R)) * 64 + e] = acc[r];
        }
    }
}

extern "C" void kernel_launch(void* const* d_in, const int* in_sizes, int n_in,
                              void* d_out, int out_size, void* d_ws, size_t ws_size,
                              hipStream_t stream) {
    const float* x  = (const float*)d_in[0];
    const float* wq = (const float*)d_in[1];
    const float* wk = (const float*)d_in[2];
    const float* wv = (const float*)d_in[3];
    const float* wo = (const float*)d_in[4];
    const float* th = (const float*)d_in[5];
    float* out = (float*)d_out;
    // B=16, S=512: 16 batches x 16 thirty-two-token groups = 256 blocks
    qattn_fused<<<dim3(256), dim3(512), 0, stream>>>(x, wq, wk, wv, wo, th, out);
}